// Round 10
// baseline (104.246 us; speedup 1.0000x reference)
//
#include <hip/hip_runtime.h>
#include <math.h>

// Problem constants: R=4, I=16, N=2048.
#define RDIM 4
#define IDIM 16
#define NPAIR 64
#define NPTS 2048
#define THREADS 256
#define ROWSB 256                   // rows per block (64 per wave)
#define RBLK (NPTS / ROWSB)         // 8
#define TILES (NPTS / 32)           // 64 col-tiles of 32
#define ONEBF 0x3F80u               // bf16(1.0)

typedef __attribute__((ext_vector_type(8))) short bf16x8;
typedef __attribute__((ext_vector_type(16))) float f32x16;

__device__ __forceinline__ unsigned int f2bf(float f) {
    union { float f; unsigned int u; } v; v.f = f;
    return (v.u + 0x7FFFu + ((v.u >> 16) & 1u)) >> 16;   // RNE bf16 (low 16 bits)
}
__device__ __forceinline__ float bf2f(unsigned int h) {
    union { unsigned int u; float f; } v; v.u = h << 16; return v.f;
}

__device__ __forceinline__ void make_rot(const float* __restrict__ rotv, int pair,
                                         float& r00, float& r01, float& r02,
                                         float& r10, float& r11, float& r12,
                                         float& r20, float& r21, float& r22) {
    const float ax = rotv[pair * 3 + 0];
    const float ay = rotv[pair * 3 + 1];
    const float az = rotv[pair * 3 + 2];
    float sx, cx, sy, cy, sz, cz;
    sincosf(ax, &sx, &cx);
    sincosf(ay, &sy, &cy);
    sincosf(az, &sz, &cz);
    r00 = cy * cz;                r01 = -cy * sz;               r02 = sy;
    r10 = cx * sz + sx * sy * cz; r11 = cx * cz - sx * sy * sz; r12 = -sx * cy;
    r20 = sx * sz - cx * sy * cz; r21 = sx * cz + cx * sy * sz; r22 = cx * cy;
}

// B-record (16 B, identical content consumed by both MFMA k-halves):
//   shorts [bh0,bh1,bh2, bl0,bl1,bl2, n2h, n2l],  b = split(-2v), n2 = |v|^2
__device__ __forceinline__ uint4 brec(float v0, float v1, float v2) {
    const float b0 = -2.0f * v0, b1 = -2.0f * v1, b2 = -2.0f * v2;
    const unsigned int h0 = f2bf(b0), h1 = f2bf(b1), h2 = f2bf(b2);
    const unsigned int l0 = f2bf(b0 - bf2f(h0));
    const unsigned int l1 = f2bf(b1 - bf2f(h1));
    const unsigned int l2 = f2bf(b2 - bf2f(h2));
    const float n2 = v0 * v0 + v1 * v1 + v2 * v2;
    const unsigned int nh = f2bf(n2), nl = f2bf(n2 - bf2f(nh));
    return make_uint4(h0 | (h1 << 16), h2 | (l0 << 16), l1 | (l2 << 16), nh | (nl << 16));
}

// K0: B-records only. blocks 0..63: transformed source -> Yb; 64..79: target -> Xb.
__global__ __launch_bounds__(THREADS)
void prep(const float* __restrict__ src, const float* __restrict__ tgt,
          const float* __restrict__ rotv, const float* __restrict__ trav,
          const float* __restrict__ scal,
          uint4* __restrict__ Yb, uint4* __restrict__ Xb)
{
    const int b = blockIdx.x;
    const int tid = threadIdx.x;
    if (b < NPAIR) {
        const int pair = b;
        float r00, r01, r02, r10, r11, r12, r20, r21, r22;
        make_rot(rotv, pair, r00, r01, r02, r10, r11, r12, r20, r21, r22);
        const float t0 = trav[pair * 3 + 0];
        const float t1 = trav[pair * 3 + 1];
        const float t2 = trav[pair * 3 + 2];
        const float s  = scal[pair];
        const float* __restrict__ srcp = src + (size_t)pair * NPTS * 3;
#pragma unroll
        for (int u = 0; u < NPTS / THREADS; ++u) {
            const int m = u * THREADS + tid;
            const float p0 = srcp[m * 3 + 0];
            const float p1 = srcp[m * 3 + 1];
            const float p2 = srcp[m * 3 + 2];
            const float y0 = s * fmaf(r00, p0, fmaf(r01, p1, fmaf(r02, p2, t0)));
            const float y1 = s * fmaf(r10, p0, fmaf(r11, p1, fmaf(r12, p2, t1)));
            const float y2 = s * fmaf(r20, p0, fmaf(r21, p1, fmaf(r22, p2, t2)));
            Yb[(size_t)pair * NPTS + m] = brec(y0, y1, y2);
        }
    } else {
        const int i = b - NPAIR;
        const float* __restrict__ tgtp = tgt + (size_t)i * NPTS * 3;
#pragma unroll
        for (int u = 0; u < NPTS / THREADS; ++u) {
            const int m = u * THREADS + tid;
            Xb[(size_t)i * NPTS + m] = brec(tgtp[m * 3 + 0], tgtp[m * 3 + 1], tgtp[m * 3 + 2]);
        }
    }
}

// K1: per (pair, rowblock, pass). Wave owns 64 rows x all 2048 cols.
// LDS = sB (32 KB) ONLY; A-fragments + own-row |q|^2 built in registers.
// Endgame: swizzled scratch overlaying sB, with a BARRIER between write and
// read phases (R8's barrier-less wave-local RAW produced scheduling-sensitive
// corruption: ~one row wrong by O(1) -> absmax 2.4e-3). Swizzle multiplier 5
// (bijective mod 32) keeps both write and read phases bank-conflict-free.
__global__ __launch_bounds__(THREADS, 4)
void chamfer_main(const float* __restrict__ src, const float* __restrict__ tgt,
                  const float* __restrict__ rotv, const float* __restrict__ trav,
                  const float* __restrict__ scal,
                  const uint4* __restrict__ Yb, const uint4* __restrict__ Xb,
                  float* __restrict__ out)
{
    __shared__ alignas(16) unsigned char smem[32768];   // sB (loop) / scratch (endgame)
    unsigned short* sB = (unsigned short*)smem;         // [2048][8] shorts
    float* scratch = (float*)smem;                      // [4 waves][32 c][64 rows] swizzled

    const int pair  = blockIdx.x;
    const int rb    = blockIdx.y;
    const int passB = blockIdx.z;  // 0: rows=target, cols=transformed; 1: swapped
    const int i     = pair & (IDIM - 1);
    const int tid   = threadIdx.x;
    const int lane  = tid & 63;
    const int w     = tid >> 6;
    const int c31   = lane & 31;
    const int h     = lane >> 5;

    // ---- stage sB: all 2048 col records (8 uint4/thread, coalesced) ----
    const uint4* __restrict__ gB = (passB == 0) ? (Yb + (size_t)pair * NPTS)
                                                : (Xb + (size_t)i * NPTS);
#pragma unroll
    for (int j = 0; j < 8; ++j)
        ((uint4*)sB)[j * THREADS + tid] = gB[j * THREADS + tid];

    // ---- rotation (wave-uniform), needed for pass 1 rows ----
    float r00, r01, r02, r10, r11, r12, r20, r21, r22, t0, t1, t2, s;
    if (passB != 0) {
        make_rot(rotv, pair, r00, r01, r02, r10, r11, r12, r20, r21, r22);
        t0 = trav[pair * 3 + 0];
        t1 = trav[pair * 3 + 1];
        t2 = trav[pair * 3 + 2];
        s  = scal[pair];
    }
    const float* __restrict__ tgtp = tgt + (size_t)i    * NPTS * 3;
    const float* __restrict__ srcp = src + (size_t)pair * NPTS * 3;

    // row-point fetch (+transform on pass 1)
    auto getq = [&](int n, float& q0, float& q1, float& q2) {
        if (passB == 0) {
            q0 = tgtp[n * 3 + 0]; q1 = tgtp[n * 3 + 1]; q2 = tgtp[n * 3 + 2];
        } else {
            const float p0 = srcp[n * 3 + 0];
            const float p1 = srcp[n * 3 + 1];
            const float p2 = srcp[n * 3 + 2];
            q0 = s * fmaf(r00, p0, fmaf(r01, p1, fmaf(r02, p2, t0)));
            q1 = s * fmaf(r10, p0, fmaf(r11, p1, fmaf(r12, p2, t1)));
            q2 = s * fmaf(r20, p0, fmaf(r21, p1, fmaf(r22, p2, t2)));
        }
    };

    // ---- own-row |q|^2 (epilogue; thread tid = block-row tid) ----
    float myq2;
    {
        float q0, q1, q2v;
        getq(rb * ROWSB + tid, q0, q1, q2v);
        myq2 = q0 * q0 + q1 * q1 + q2v * q2v;
    }

    // ---- A fragments built in registers: lane supplies row c31, k-half h ----
    // half0 = [qh0,qh1,qh2, ql0,ql1,ql2, 1, 0]; half1 = [ql0,ql1,ql2, qh0,qh1,qh2, 0, 1]
    auto buildA = [&](int n) -> bf16x8 {
        float q0, q1, q2v;
        getq(n, q0, q1, q2v);
        const unsigned int h0 = f2bf(q0), h1 = f2bf(q1), h2 = f2bf(q2v);
        const unsigned int l0 = f2bf(q0 - bf2f(h0));
        const unsigned int l1 = f2bf(q1 - bf2f(h1));
        const unsigned int l2 = f2bf(q2v - bf2f(h2));
        union { uint4 u; bf16x8 v; } cv;
        if (h == 0)
            cv.u = make_uint4(h0 | (h1 << 16), h2 | (l0 << 16), l1 | (l2 << 16), ONEBF);
        else
            cv.u = make_uint4(l0 | (l1 << 16), l2 | (h0 << 16), h1 | (h2 << 16), ONEBF << 16);
        return cv.v;
    };
    const bf16x8 af0 = buildA(rb * ROWSB + w * 64 + c31);
    const bf16x8 af1 = buildA(rb * ROWSB + w * 64 + 32 + c31);

    float mn0[16], mn1[16];
#pragma unroll
    for (int j = 0; j < 16; ++j) { mn0[j] = 3.4e38f; mn1[j] = 3.4e38f; }

    const f32x16 zero16 = {0,0,0,0, 0,0,0,0, 0,0,0,0, 0,0,0,0};

    __syncthreads();   // sB staged

    // ---- main loop: 2 tiles/step; fminf(fminf(..)) -> compiler v_min3 ----
#pragma unroll 2
    for (int t2 = 0; t2 < TILES / 2; ++t2) {
        const bf16x8 bfA = *(const bf16x8*)&sB[((t2 * 2 + 0) * 32 + c31) * 8];
        const bf16x8 bfB = *(const bf16x8*)&sB[((t2 * 2 + 1) * 32 + c31) * 8];
        const f32x16 d0a = __builtin_amdgcn_mfma_f32_32x32x16_bf16(af0, bfA, zero16, 0, 0, 0);
        const f32x16 d0b = __builtin_amdgcn_mfma_f32_32x32x16_bf16(af0, bfB, zero16, 0, 0, 0);
#pragma unroll
        for (int j = 0; j < 16; ++j)
            mn0[j] = fminf(mn0[j], fminf(d0a[j], d0b[j]));
        const f32x16 d1a = __builtin_amdgcn_mfma_f32_32x32x16_bf16(af1, bfA, zero16, 0, 0, 0);
        const f32x16 d1b = __builtin_amdgcn_mfma_f32_32x32x16_bf16(af1, bfB, zero16, 0, 0, 0);
#pragma unroll
        for (int j = 0; j < 16; ++j)
            mn1[j] = fminf(mn1[j], fminf(d1a[j], d1b[j]));
    }
    __syncthreads();   // all waves done with sB; scratch overlays it

    // ---- endgame: write swizzled scratch ----
    // local row of mn{rt}[j]: r = rt*32 + 8*(j>>2) + 4*h + (j&3); col-class c31.
    // scratch[w][c][(r + 5c) & 63]: multiplier 5 -> conflict-free b32 writes & reads.
    float* sw = &scratch[w * 2048];
#pragma unroll
    for (int j = 0; j < 16; ++j) {
        const int r0 = 8 * (j >> 2) + 4 * h + (j & 3);
        sw[c31 * 64 + ((r0 + 5 * c31) & 63)]      = mn0[j];
        sw[c31 * 64 + ((r0 + 32 + 5 * c31) & 63)] = mn1[j];
    }
    __syncthreads();   // drain scratch writes before the transposed reads

    // ---- thread tid = block-row tid: min over 32 col-classes + |q|^2 ----
    float m = 3.4e38f;
#pragma unroll
    for (int c = 0; c < 32; ++c)
        m = fminf(m, sw[c * 64 + ((lane + 5 * c) & 63)]);
    float v = m + myq2;

#pragma unroll
    for (int off = 32; off > 0; off >>= 1)
        v += __shfl_down(v, off, 64);
    if (lane == 0)
        atomicAdd(&out[pair], v * (1.0f / NPTS));
}

extern "C" void kernel_launch(void* const* d_in, const int* in_sizes, int n_in,
                              void* d_out, int out_size, void* d_ws, size_t ws_size,
                              hipStream_t stream) {
    const float* src  = (const float*)d_in[0];  // [4,16,2048,3]
    const float* tgt  = (const float*)d_in[1];  // [16,2048,3]
    const float* rotv = (const float*)d_in[2];  // [4,16,3]
    const float* trav = (const float*)d_in[3];  // [4,16,3]
    const float* scal = (const float*)d_in[4];  // [4,16]
    float* out = (float*)d_out;                 // [4,16]

    // ws: Yb 2 MB | Xb 0.5 MB
    char* ws = (char*)d_ws;
    uint4* Yb = (uint4*)ws;
    uint4* Xb = (uint4*)(ws + (size_t)NPAIR * NPTS * 16);

    hipMemsetAsync(out, 0, NPAIR * sizeof(float), stream);

    prep<<<NPAIR + IDIM, THREADS, 0, stream>>>(src, tgt, rotv, trav, scal, Yb, Xb);

    dim3 grid(NPAIR, RBLK, 2);
    chamfer_main<<<grid, THREADS, 0, stream>>>(src, tgt, rotv, trav, scal, Yb, Xb, out);
}